// Round 3
// 76.314 us; speedup vs baseline: 1.2926x; 1.2926x over previous
//
#include <hip/hip_runtime.h>

typedef short short8 __attribute__((ext_vector_type(8)));
typedef float floatx16 __attribute__((ext_vector_type(16)));

#define B_    4
#define NPTS  8192          // N == M == 8192
#define IS    16            // i-splits (512 src per block)
#define JS    16            // j-splits (512 dst per block)
#define ITB   512
#define JTB   512
#define NT    4             // i-tiles (32 wide) per wave -> 128 i/wave
#define NJT   16            // j-tiles (32 wide) per block
#define TOT   (B_ * NPTS)   // 32768

// LDS offsets in short8 units. A0/A1: dst k0..7 / k8..15. B0/B1: src.
// K=16 exactly matches mfma_f32_32x32x16_bf16 -> no zero block needed.
#define A0OFF 0
#define A1OFF 516           // +4 pad blocks: bank-stagger the two k-halves
#define B0OFF 1032
#define B1OFF 1548
#define LDS8N 2060          // 32,960 B -> 4 blocks/CU

// ws: slots uint32[2*TOT] = 256 KiB, memset 0xFF. Monotone float->uint map.

__device__ __forceinline__ unsigned short bf16h(float v) {
  unsigned u = __float_as_uint(v);
  return (unsigned short)((u + 0x7FFFu + ((u >> 16) & 1u)) >> 16);   // RNE
}
__device__ __forceinline__ void bf16split(float v, unsigned short& h, unsigned short& l) {
  h = bf16h(v);
  l = bf16h(v - __uint_as_float((unsigned)h << 16));
}

// K-slot scheme (k0..15, all real):
//   A (dst j): k0..7  [axh axh axl axl  ayh ayh ayl ayl]      a = -2g
//              k8..15 [azh azh azl azl  wh  wl  1   1 ]       w = ||g||^2
//   B (src i): k0..7  [pxh pxl pxh pxl  pyh pyl pyh pyl]
//              k8..15 [pzh pzl pzh pzl  1   1   qh  ql]       q = ||p||^2
// Sum_k A[j][k]B[k][i] = -2<g,p> + ||g||^2 + ||p||^2 = squared distance.
// (hi*hi etc products are exact in fp32: 8b x 8b mantissas; split err ~2^-17)
__device__ __forceinline__ void pack_dst(const float* g, short8& s0, short8& s1) {
  const float x = g[0], y = g[1], z = g[2];
  const float w = fmaf(x, x, fmaf(y, y, z * z));
  unsigned short xh, xl, yh, yl, zh, zl, wh, wl;
  bf16split(-2.f * x, xh, xl); bf16split(-2.f * y, yh, yl);
  bf16split(-2.f * z, zh, zl); bf16split(w, wh, wl);
  s0 = (short8){(short)xh,(short)xh,(short)xl,(short)xl,
                (short)yh,(short)yh,(short)yl,(short)yl};
  s1 = (short8){(short)zh,(short)zh,(short)zl,(short)zl,
                (short)wh,(short)wl,(short)0x3F80,(short)0x3F80};
}
__device__ __forceinline__ void pack_src(const float* p, short8& s0, short8& s1) {
  const float x = p[0], y = p[1], z = p[2];
  const float qq = fmaf(x, x, fmaf(y, y, z * z));
  unsigned short xh, xl, yh, yl, zh, zl, qh, ql;
  bf16split(x, xh, xl); bf16split(y, yh, yl);
  bf16split(z, zh, zl); bf16split(qq, qh, ql);
  s0 = (short8){(short)xh,(short)xl,(short)xh,(short)xl,
                (short)yh,(short)yl,(short)yh,(short)yl};
  s1 = (short8){(short)zh,(short)zl,(short)zh,(short)zl,
                (short)0x3F80,(short)0x3F80,(short)qh,(short)ql};
}

// grid (IS, JS, 2*B_) = (16,16,8) = 2048 blocks, 256 thr (4 waves).
// Block: 512 i x 512 j. Wave w: i in [w*128, w*128+128), all 512 j.
// mfma_f32_32x32x16_bf16 operand layout (m74/m101 verified):
//   A[row][k]: row = lane&31, k = 8*(lane>>5)+e  -> half 0 reads A0, half 1 A1
//   B[k][col]: col = lane&31, k = 8*(lane>>5)+e  -> half 0 reads B0, half 1 B1
//   D[row][col]: col = lane&31, row = (reg&3)+8*(reg>>2)+4*(lane>>5)
// Each lane min-folds its 16 rows; shfl_xor(32) merges the two row-halves.
// NO inline asm on MFMA outputs: the compiler's hazard recognizer only checks
// inline-asm DEFS, not USES, of MFMA-written VGPRs (R1/R2 failure cause).
// Nested fminf lets ISel fuse to v_min3_f32 where legal.
__global__ __launch_bounds__(256, 4) void mfma_pass_kernel(
    const float* __restrict__ pred, const float* __restrict__ gt,
    unsigned* __restrict__ slots) {
  __shared__ short8 lds8[LDS8N];

  const int zb  = blockIdx.z;
  const int dir = zb >> 2;
  const int b   = zb & 3;
  const float* src = dir ? gt   : pred;   // i-cloud (min FOR these)
  const float* dst = dir ? pred : gt;     // j-cloud (min OVER these)

  const int tid   = threadIdx.x;
  const int lane  = tid & 63;
  const int w     = tid >> 6;
  const int jbase = blockIdx.y * JTB;
  const int ibase = blockIdx.x * ITB;

  // Stage both tiles: 512 dst + 512 src points, 2 each per thread.
#pragma unroll
  for (int r = 0; r < 2; ++r) {
    const int pt = tid + r * 256;
    short8 s0, s1;
    pack_dst(dst + ((size_t)b * NPTS + jbase + pt) * 3, s0, s1);
    lds8[A0OFF + pt] = s0;
    lds8[A1OFF + pt] = s1;
    pack_src(src + ((size_t)b * NPTS + ibase + pt) * 3, s0, s1);
    lds8[B0OFF + pt] = s0;
    lds8[B1OFF + pt] = s1;
  }
  __syncthreads();

  const int n = lane & 31;       // point index within 32-tile (A: j, B: i)
  const int h = lane >> 5;       // k-half: 0 -> k0..7, 1 -> k8..15

  // B fragments: one-time loads.
  short8 bf[NT];
  float  ma[NT], mb[NT];         // two independent min chains per tile
  const int bbase = (h ? B1OFF : B0OFF) + w * 128 + n;
#pragma unroll
  for (int t = 0; t < NT; ++t) {
    bf[t] = lds8[bbase + t * 32];
    ma[t] = 1e30f;
    mb[t] = 1e30f;
  }

  const int abase = (h ? A1OFF : A0OFF) + n;
  const floatx16 zero16 = {0.f,0.f,0.f,0.f, 0.f,0.f,0.f,0.f,
                           0.f,0.f,0.f,0.f, 0.f,0.f,0.f,0.f};

  for (int jt = 0; jt < NJT; ++jt) {
    const short8 af = lds8[abase + jt * 32];
#pragma unroll
    for (int t = 0; t < NT; ++t) {
      floatx16 d = __builtin_amdgcn_mfma_f32_32x32x16_bf16(af, bf[t], zero16, 0, 0, 0);
      // Two independent 8-value chains; each nest is min(min(a,b),c)-shaped
      // so ISel can fuse to v_min3_f32 (8 min3 total if fused, 16 min else).
      float ca = fminf(fminf(d[0], d[1]), d[2]);
      ca = fminf(fminf(ca, d[3]), d[4]);
      ca = fminf(fminf(ca, d[5]), d[6]);
      ma[t] = fminf(fminf(ca, d[7]), ma[t]);
      float cb = fminf(fminf(d[8], d[9]), d[10]);
      cb = fminf(fminf(cb, d[11]), d[12]);
      cb = fminf(fminf(cb, d[13]), d[14]);
      mb[t] = fminf(fminf(cb, d[15]), mb[t]);
    }
  }

  // Merge the two row-halves (lanes n and n+32 hold complementary j-rows of
  // the same column i=n), then ONE atomicMin per (i, block).
#pragma unroll
  for (int t = 0; t < NT; ++t) {
    float v = fminf(ma[t], mb[t]);
    v = fminf(v, __shfl_xor(v, 32));
    if (lane < 32) {
      const int gi = ibase + w * 128 + t * 32 + lane;
      const int bi = __float_as_int(v);
      const unsigned u = (unsigned)bi ^ (unsigned)((bi >> 31) | 0x80000000);
      atomicMin(&slots[(size_t)(dir * B_ + b) * NPTS + gi], u);
    }
  }
}

// Sweep 2*TOT slots, decode, reduce, one atomic per block.  (proven)
__global__ __launch_bounds__(256) void pass2_kernel(
    const unsigned* __restrict__ slots, float* __restrict__ out) {
  const int gid = blockIdx.x * 256 + threadIdx.x;   // 8192 threads
  float s = 0.f;
#pragma unroll
  for (int k = 0; k < 8; ++k) {
    const unsigned u = slots[gid + k * 8192];
    const int bi = (u & 0x80000000u) ? (int)(u ^ 0x80000000u) : (int)~u;
    s += __int_as_float(bi);
  }
  __shared__ float red[256];
  const int tid = threadIdx.x;
  red[tid] = s;
  __syncthreads();
  for (int st = 128; st > 0; st >>= 1) {
    if (tid < st) red[tid] += red[tid + st];
    __syncthreads();
  }
  if (tid == 0) atomicAdd(out, red[0] * (1.0f / TOT));
}

extern "C" void kernel_launch(void* const* d_in, const int* in_sizes, int n_in,
                              void* d_out, int out_size, void* d_ws, size_t ws_size,
                              hipStream_t stream) {
  const float* pred = (const float*)d_in[0];
  const float* gt   = (const float*)d_in[1];
  unsigned* slots = (unsigned*)d_ws;
  float* out = (float*)d_out;

  hipMemsetAsync(slots, 0xFF, (size_t)2 * TOT * sizeof(unsigned), stream);
  hipMemsetAsync(out, 0, out_size * sizeof(float), stream);

  dim3 g(IS, JS, 2 * B_);   // 2048 blocks
  mfma_pass_kernel<<<g, 256, 0, stream>>>(pred, gt, slots);

  pass2_kernel<<<(2 * TOT) / (256 * 8), 256, 0, stream>>>(slots, out);
}